// Round 24
// baseline (210.996 us; speedup 1.0000x reference)
//
#include <hip/hip_runtime.h>
#include <math.h>

#define T_SEQ 2048
#define NH 16
#define HD 64
#define EMB 1024
#define NBATCH 4
#define M_ROWS 8192  // NBATCH*T_SEQ

typedef __attribute__((ext_vector_type(8))) short short8;
typedef __attribute__((ext_vector_type(4))) float f32x4;

__device__ __forceinline__ unsigned short f2bf(float f) {
  unsigned int u = __float_as_uint(f);
  u += 0x7FFF + ((u >> 16) & 1);
  return (unsigned short)(u >> 16);
}

__device__ __forceinline__ float fast_exp2(float x) {
  float r;
  asm("v_exp_f32 %0, %1" : "=v"(r) : "v"(x));
  return r;
}

__device__ __forceinline__ void load_lds16(const void* g, void* l) {
  __builtin_amdgcn_global_load_lds((const __attribute__((address_space(1))) void*)g,
                                   (__attribute__((address_space(3))) void*)l, 16, 0, 0);
}

#define BARR __builtin_amdgcn_s_barrier()
#define LGKM0 asm volatile("s_waitcnt lgkmcnt(0)" ::: "memory")

// ---------------- fused prep (R23, verified) ----------------
__device__ __forceinline__ void cvtT_tile(const float* __restrict__ w,
                                          unsigned short* __restrict__ wt,
                                          int K, int N, int bx, int by,
                                          unsigned short (*tile)[66], int tid) {
  const int k0 = by * 64, n0 = bx * 64;
  const int tc = (tid & 15) * 4;
  const int tr = tid >> 4;
#pragma unroll
  for (int p = 0; p < 4; ++p) {
    const int kr = p * 16 + tr;
    float4 v = *reinterpret_cast<const float4*>(&w[(size_t)(k0 + kr) * N + n0 + tc]);
    tile[kr][tc + 0] = f2bf(v.x); tile[kr][tc + 1] = f2bf(v.y);
    tile[kr][tc + 2] = f2bf(v.z); tile[kr][tc + 3] = f2bf(v.w);
  }
  __syncthreads();
#pragma unroll
  for (int p = 0; p < 4; ++p) {
    const int nr = p * 16 + tr;
    ushort4 o;
    o.x = tile[tc + 0][nr]; o.y = tile[tc + 1][nr];
    o.z = tile[tc + 2][nr]; o.w = tile[tc + 3][nr];
    *reinterpret_cast<ushort4*>(&wt[(size_t)(n0 + nr) * K + k0 + tc]) = o;
  }
}

__global__ __launch_bounds__(256) void k_prep(
    const float* __restrict__ x, unsigned short* __restrict__ xb,
    const float* __restrict__ wqkv, unsigned short* __restrict__ wqkvT,
    const float* __restrict__ wproj, unsigned short* __restrict__ wprojT)
{
  __shared__ unsigned short tile[64][66];
  const int tid = threadIdx.x;
  const int bid = blockIdx.x;

  if (bid < 8192) {
    const int i = bid * 256 + tid;
    float4 v = reinterpret_cast<const float4*>(x)[i];
    ushort4 o;
    o.x = f2bf(v.x); o.y = f2bf(v.y); o.z = f2bf(v.z); o.w = f2bf(v.w);
    reinterpret_cast<ushort4*>(xb)[i] = o;
  } else if (bid < 8960) {
    const int b2 = bid - 8192;
    cvtT_tile(wqkv, wqkvT, EMB, 3 * EMB, b2 % 48, b2 / 48, tile, tid);
  } else {
    const int b2 = bid - 8960;
    cvtT_tile(wproj, wprojT, EMB, EMB, b2 % 16, b2 / 16, tile, tid);
  }
}

// ---------------- GEMM A: 256x256 BK=64, FAITHFUL m201 8-phase schedule (QKV) ----------------
// Data path = R19 (correctness-verified).  Per phase: {ds_read this phase's frags; stage one
// half-tile; s_barrier; lgkmcnt(0); setprio(1); 16 MFMA; setprio(0); s_barrier}.  ds_reads
// issue BEFORE the barrier (latency hides under barrier-wait); end-of-phase barrier makes
// staging race-free (reads retire at lgkm before it).  Fixed slots: even K-tiles in slot E,
// odd in slot O.  Stage schedule per iteration (computes t0 at P0-3 from E, t0+1 at P4-7
// from O):  P0,P1: A(t0+1)->O (overwrites A(t0-1), reads ended prev P7)
//           P2,P3: B(t0+2)->E (overwrites B(t0), frag-read at P0)
//           P4,P5: A(t0+2)->E (overwrites A(t0), reads ended P3)
//           P6,P7: B(t0+3)->O (overwrites B(t0+1), frag-read at P4)
// Waits: vmcnt(4) before P3 end-barrier (outstanding A(t0+1)4+B(t0+2)4 -> retires A(t0+1),
// needed at P4) and before P7 end-barrier (retires B(t0+2),A(t0+2), needed next P0; leaves
// B(t0+3) in flight).  Tail: skipped stages -> vmcnt(0).  Prologue: B(0),A(0),B(1); vmcnt(4)
// -> steady state (B(1) in flight).  128KB LDS, 1 block/CU, 512 thr.
#define HSLOT 8192    // shorts per 16KB half (128 rows x 64)
#define SLOT8 32768   // shorts per slot [A0|A1|B0|B1]

template <int MODE>
__global__ __launch_bounds__(512, 2) void k_gemm8p(
    const unsigned short* __restrict__ A,
    const unsigned short* __restrict__ Bt,
    const float* __restrict__ bias,
    float* __restrict__ Cout,
    unsigned short* __restrict__ qh, unsigned short* __restrict__ kh,
    unsigned short* __restrict__ vh,
    int N, int K)
{
  extern __shared__ __align__(16) unsigned short lds[];  // 2 * SLOT8

  const int tid = threadIdx.x;
  const int w = tid >> 6, lane = tid & 63;
  const int lo = lane & 15, hi = lane >> 4;
  const int wm = w >> 2, wn = w & 3;

  const int nwg = gridDim.x * gridDim.y;
  int flat = blockIdx.y * gridDim.x + blockIdx.x;
  flat = (flat & 7) * (nwg >> 3) + (flat >> 3);
  const int tm = flat / gridDim.x, tn = flat % gridDim.x;

  const int r0 = tid >> 3;
  const int scol = ((tid & 7) ^ (r0 & 7)) * 8;
  const unsigned short* Asrc = A  + (size_t)(tm * 256 + r0) * K + scol;
  const unsigned short* Bsrc = Bt + (size_t)(tn * 256 + r0) * K + scol;
  const int dsto = tid * 8;

  const int nkb = K >> 6;
  const int swz = lo & 7;

  unsigned short* eS = lds;
  unsigned short* oS = lds + SLOT8;
  const unsigned short* sAe = eS + wm * HSLOT;
  const unsigned short* sBe = eS + 2 * HSLOT + (wn >> 1) * HSLOT;
  const unsigned short* sAo = oS + wm * HSLOT;
  const unsigned short* sBo = oS + 2 * HSLOT + (wn >> 1) * HSLOT;
  const int brow = (wn & 1) * 64;

  f32x4 acc[8][4] = {};
  short8 a[2][2], bf[2][4];

  auto stgA = [&](int kstep, int half, unsigned short* slot) {
    const unsigned short* s = Asrc + (size_t)(half * 128) * K + (kstep << 6);
    unsigned short* d = slot + half * HSLOT + dsto;
    load_lds16(s, d);
    load_lds16(s + (size_t)64 * K, d + 4096);
  };
  auto stgB = [&](int kstep, int half, unsigned short* slot) {
    const unsigned short* s = Bsrc + (size_t)(half * 128) * K + (kstep << 6);
    unsigned short* d = slot + 2 * HSLOT + half * HSLOT + dsto;
    load_lds16(s, d);
    load_lds16(s + (size_t)64 * K, d + 4096);
  };
  auto rdA = [&](const unsigned short* sAh, int q) {
#pragma unroll
    for (int i = 0; i < 2; ++i)
#pragma unroll
      for (int kk = 0; kk < 2; ++kk)
        a[i][kk] = *reinterpret_cast<const short8*>(
            &sAh[((q * 2 + i) * 16 + lo) * 64 + ((kk * 4 + hi) ^ swz) * 8]);
  };
  auto rdB = [&](const unsigned short* sBh) {
#pragma unroll
    for (int kk = 0; kk < 2; ++kk)
#pragma unroll
      for (int n = 0; n < 4; ++n)
        bf[kk][n] = *reinterpret_cast<const short8*>(
            &sBh[(brow + n * 16 + lo) * 64 + ((kk * 4 + hi) ^ swz) * 8]);
  };
  auto mm = [&](int q) {
    __builtin_amdgcn_s_setprio(1);
#pragma unroll
    for (int i = 0; i < 2; ++i)
#pragma unroll
      for (int n = 0; n < 4; ++n) {
        acc[q * 2 + i][n] = __builtin_amdgcn_mfma_f32_16x16x32_bf16(a[i][0], bf[0][n], acc[q * 2 + i][n], 0, 0, 0);
        acc[q * 2 + i][n] = __builtin_amdgcn_mfma_f32_16x16x32_bf16(a[i][1], bf[1][n], acc[q * 2 + i][n], 0, 0, 0);
      }
    __builtin_amdgcn_s_setprio(0);
  };

  // prologue: B(0),A(0) -> E; B(1) -> O; land B(0),A(0)
  stgB(0, 0, eS); stgB(0, 1, eS);
  stgA(0, 0, eS); stgA(0, 1, eS);
  if (nkb > 1) { stgB(1, 0, oS); stgB(1, 1, oS); }
  if (nkb > 1) asm volatile("s_waitcnt vmcnt(4)" ::: "memory");
  else         asm volatile("s_waitcnt vmcnt(0)" ::: "memory");
  BARR;

  for (int it = 0; it < (nkb >> 1); ++it) {
    const int t0 = it * 2;
    // ---- K-tile t0 (slot E) ----
    rdB(sBe); rdA(sAe, 0);                       // P0: 12 ds_read
    stgA(t0 + 1, 0, oS);
    BARR; LGKM0; mm(0); BARR;

    rdA(sAe, 1);                                 // P1
    stgA(t0 + 1, 1, oS);
    BARR; LGKM0; mm(1); BARR;

    rdA(sAe, 2);                                 // P2
    if (t0 + 2 < nkb) stgB(t0 + 2, 0, eS);
    BARR; LGKM0; mm(2); BARR;

    rdA(sAe, 3);                                 // P3
    if (t0 + 2 < nkb) stgB(t0 + 2, 1, eS);
    BARR; LGKM0; mm(3);
    if (t0 + 2 < nkb) asm volatile("s_waitcnt vmcnt(4)" ::: "memory");
    else              asm volatile("s_waitcnt vmcnt(0)" ::: "memory");
    BARR;                                        // A(t0+1) landed for all

    // ---- K-tile t0+1 (slot O) ----
    rdB(sBo); rdA(sAo, 0);                       // P4
    if (t0 + 2 < nkb) stgA(t0 + 2, 0, eS);
    BARR; LGKM0; mm(0); BARR;

    rdA(sAo, 1);                                 // P5
    if (t0 + 2 < nkb) stgA(t0 + 2, 1, eS);
    BARR; LGKM0; mm(1); BARR;

    rdA(sAo, 2);                                 // P6
    if (t0 + 3 < nkb) stgB(t0 + 3, 0, oS);
    BARR; LGKM0; mm(2); BARR;

    rdA(sAo, 3);                                 // P7
    if (t0 + 3 < nkb) stgB(t0 + 3, 1, oS);
    BARR; LGKM0; mm(3);
    if (t0 + 3 < nkb) asm volatile("s_waitcnt vmcnt(4)" ::: "memory");
    else              asm volatile("s_waitcnt vmcnt(0)" ::: "memory");
    BARR;                                        // B(t0+2),A(t0+2) landed for all
  }

#pragma unroll
  for (int m = 0; m < 8; ++m) {
#pragma unroll
    for (int n = 0; n < 4; ++n) {
      const int col = tn * 256 + wn * 64 + n * 16 + lo;
      const float bs = bias[col];
#pragma unroll
      for (int r = 0; r < 4; ++r) {
        const int row = tm * 256 + wm * 128 + m * 16 + hi * 4 + r;
        const float v = acc[m][n][r] + bs;
        if (MODE == 0) {
          Cout[(size_t)row * N + col] = v;
        } else {
          const int sec = col >> 10, jj = col & 1023;
          const int hh = jj >> 6, d = jj & 63;
          const int b2 = row >> 11, tt = row & 2047;
          if (sec == 2) {
            vh[(size_t)((b2 * NH + hh) * HD + d) * T_SEQ + tt] = f2bf(v);  // V^T [B,H,d,T]
          } else {
            unsigned short* dst = sec == 0 ? qh : kh;
            dst[(size_t)((b2 * NH + hh) * T_SEQ + tt) * HD + d] = f2bf(v);
          }
        }
      }
    }
  }
}

// ---------------- GEMM B: m97-replica 128x128 (R21/R23, verified) — proj ----------------
template <int MODE>
__global__ __launch_bounds__(256, 4) void k_gemmq(
    const unsigned short* __restrict__ A,
    const unsigned short* __restrict__ Bt,
    const float* __restrict__ bias,
    float* __restrict__ Cout,
    unsigned short* __restrict__ qh, unsigned short* __restrict__ kh,
    unsigned short* __restrict__ vh,
    int N, int K)
{
  __shared__ __align__(16) unsigned short sA[128 * 64];
  __shared__ __align__(16) unsigned short sB[128 * 64];

  const int tid = threadIdx.x;
  const int w = tid >> 6, lane = tid & 63;
  const int lo = lane & 15, hi = lane >> 4;
  const int wm = w >> 1, wn = w & 1;

  const int nwg = gridDim.x * gridDim.y;
  int flat = blockIdx.y * gridDim.x + blockIdx.x;
  flat = (flat & 7) * (nwg >> 3) + (flat >> 3);
  const int tm = flat / gridDim.x, tn = flat % gridDim.x;

  const int r0 = tid >> 3;
  const int scol = ((tid & 7) ^ (r0 & 7)) * 8;
  const unsigned short* Ab = A  + (size_t)(tm * 128 + r0) * K + scol;
  const unsigned short* Bb = Bt + (size_t)(tn * 128 + r0) * K + scol;
  const int dsto = tid * 8;

  const int nkb = K >> 6;
  const int swz = lo & 7;

  f32x4 acc[4][4] = {};

  for (int kb = 0; kb < nkb; ++kb) {
    __syncthreads();
    const int k0 = kb << 6;
#pragma unroll
    for (int i = 0; i < 4; ++i) {
      load_lds16(Ab + (size_t)(i * 32) * K + k0, sA + i * 2048 + dsto);
      load_lds16(Bb + (size_t)(i * 32) * K + k0, sB + i * 2048 + dsto);
    }
    __syncthreads();

#pragma unroll
    for (int kk = 0; kk < 2; ++kk) {
      short8 a[4], b[4];
#pragma unroll
      for (int m = 0; m < 4; ++m)
        a[m] = *reinterpret_cast<const short8*>(
            &sA[(wm * 64 + m * 16 + lo) * 64 + ((kk * 4 + hi) ^ swz) * 8]);
#pragma unroll
      for (int n = 0; n < 4; ++n)
        b[n] = *reinterpret_cast<const short8*>(
            &sB[(wn * 64 + n * 16 + lo) * 64 + ((kk * 4 + hi) ^ swz) * 8]);
      __builtin_amdgcn_s_setprio(1);
#pragma unroll
      for (int m = 0; m < 4; ++m)
#pragma unroll
        for (int n = 0; n < 4; ++n)
          acc[m][n] = __builtin_amdgcn_mfma_f32_16x16x32_bf16(a[m], b[n], acc[m][n], 0, 0, 0);
      __builtin_amdgcn_s_setprio(0);
    }
  }

#pragma unroll
  for (int m = 0; m < 4; ++m) {
#pragma unroll
    for (int n = 0; n < 4; ++n) {
      const int col = tn * 128 + wn * 64 + n * 16 + lo;
      const float bs = bias[col];
#pragma unroll
      for (int r = 0; r < 4; ++r) {
        const int row = tm * 128 + wm * 64 + m * 16 + hi * 4 + r;
        const float v = acc[m][n][r] + bs;
        if (MODE == 0) {
          Cout[(size_t)row * N + col] = v;
        } else {
          const int sec = col >> 10, jj = col & 1023;
          const int hh = jj >> 6, d = jj & 63;
          const int b2 = row >> 11, tt = row & 2047;
          if (sec == 2) {
            vh[(size_t)((b2 * NH + hh) * HD + d) * T_SEQ + tt] = f2bf(v);
          } else {
            unsigned short* dst = sec == 0 ? qh : kh;
            dst[(size_t)((b2 * NH + hh) * T_SEQ + tt) * HD + d] = f2bf(v);
          }
        }
      }
    }
  }
}

// ---------------- flash attention (R16, verified) ----------------
#define C1 0.1803368801111f
#define M2 12.0f

__device__ __forceinline__ void stage2(const unsigned short* src, const int off[2],
                                       unsigned short* dstbase, int w) {
#pragma unroll
  for (int j = 0; j < 2; ++j)
    load_lds16(src + off[j], dstbase + (2 * w + j) * 512);
}

template <bool FIRST, bool LAST>
__device__ __forceinline__ void attn_tile(
    int kvb, int nkvb,  // BOTH in kv-row units
    int qw, int w, int lo, int hi,
    const short8& aq0, const short8& aq1,
    const unsigned short* __restrict__ Kp,
    const unsigned short* __restrict__ VT,
    const int koff[2], const int voff[2],
    unsigned short* kc, unsigned short* kn, unsigned short* vc,
    unsigned short* pw,
    f32x4 o[4], float lsum[4])
{
  {
    const int vb2[2] = {kvb + voff[0], kvb + voff[1]};
    stage2(VT, vb2, vc, w);
  }
  if (!LAST) {
    const int kb2[2] = {nkvb * HD + koff[0], nkvb * HD + koff[1]};
    stage2(Kp, kb2, kn, w);
  }

  if (FIRST)
    asm volatile("s_waitcnt vmcnt(0)\n\ts_barrier" ::: "memory");

  const int swz = lo & 7;
  f32x4 s[4];
#pragma unroll
  for (int n = 0; n < 4; ++n) {
    const int row = (n * 16 + lo) * 64;
    short8 bk0 = *reinterpret_cast<const short8*>(&kc[row + ((hi) ^ swz) * 8]);
    short8 bk1 = *reinterpret_cast<const short8*>(&kc[row + ((4 + hi) ^ swz) * 8]);
    f32x4 z = {};
    z = __builtin_amdgcn_mfma_f32_16x16x32_bf16(aq0, bk0, z, 0, 0, 0);
    s[n] = __builtin_amdgcn_mfma_f32_16x16x32_bf16(aq1, bk1, z, 0, 0, 0);
  }

  const int lb3 = lo >> 3, l7 = lo & 7;
#pragma unroll
  for (int r = 0; r < 4; ++r) {
    const int qrow = qw + hi * 4 + r;
    const int q = hi * 4 + r, qk7 = q & 7;
#pragma unroll
    for (int n = 0; n < 4; ++n) {
      float e = fast_exp2(fmaf(s[n][r], C1, -M2));
      if (LAST) {
        const int kv = kvb + n * 16 + lo;
        if (kv > qrow) e = 0.f;
      }
      lsum[r] += e;
      pw[q * 64 + (((n * 2 + lb3) ^ qk7) * 8) + l7] = f2bf(e);
    }
  }

  asm volatile("s_waitcnt vmcnt(0)\n\ts_barrier" ::: "memory");

#pragma unroll
  for (int kk = 0; kk < 2; ++kk) {
    short8 ap = *reinterpret_cast<const short8*>(&pw[lo * 64 + ((kk * 4 + hi) ^ swz) * 8]);
#pragma unroll
    for (int n = 0; n < 4; ++n) {
      const int row = (n * 16 + lo) * 64;
      short8 bv = *reinterpret_cast<const short8*>(&vc[row + ((kk * 4 + hi) ^ swz) * 8]);
      o[n] = __builtin_amdgcn_mfma_f32_16x16x32_bf16(ap, bv, o[n], 0, 0, 0);
    }
  }
}

__device__ __forceinline__ void attn_phase(
    int qb, int w, int lo, int hi,
    const unsigned short* __restrict__ Q,
    const unsigned short* __restrict__ Kp,
    const unsigned short* __restrict__ VT,
    const int koff[2], const int voff[2],
    unsigned short* kbuf0, unsigned short* kbuf1,
    unsigned short* vbuf0, unsigned short* vbuf1,
    unsigned short* pw,
    unsigned short* __restrict__ y, int b, int h)
{
  __builtin_amdgcn_s_barrier();

  const int qw = qb * 64 + w * 16;

  short8 aq0 = *reinterpret_cast<const short8*>(Q + (size_t)(qw + lo) * HD + hi * 8);
  short8 aq1 = *reinterpret_cast<const short8*>(Q + (size_t)(qw + lo) * HD + 32 + hi * 8);

  f32x4 o[4] = {};
  float lsum[4] = {0.f, 0.f, 0.f, 0.f};

  {
    const int kb2[2] = {koff[0], koff[1]};
    stage2(Kp, kb2, kbuf0, w);
  }

  const int nt = qb + 1;
  if (nt == 1) {
    attn_tile<true, true>(0, 0, qw, w, lo, hi, aq0, aq1, Kp, VT, koff, voff,
                          kbuf0, kbuf1, vbuf0, pw, o, lsum);
  } else {
    attn_tile<true, false>(0, 64, qw, w, lo, hi, aq0, aq1, Kp, VT, koff, voff,
                           kbuf0, kbuf1, vbuf0, pw, o, lsum);
    for (int t = 1; t < nt - 1; ++t) {
      unsigned short* kc = (t & 1) ? kbuf1 : kbuf0;
      unsigned short* kn = (t & 1) ? kbuf0 : kbuf1;
      unsigned short* vc = (t & 1) ? vbuf1 : vbuf0;
      attn_tile<false, false>(t * 64, (t + 1) * 64, qw, w, lo, hi, aq0, aq1, Kp, VT,
                              koff, voff, kc, kn, vc, pw, o, lsum);
    }
    const int t = nt - 1;
    unsigned short* kc = (t & 1) ? kbuf1 : kbuf0;
    unsigned short* kn = (t & 1) ? kbuf0 : kbuf1;
    unsigned short* vc = (t & 1) ? vbuf1 : vbuf0;
    attn_tile<false, true>(t * 64, 0, qw, w, lo, hi, aq0, aq1, Kp, VT, koff, voff,
                           kc, kn, vc, pw, o, lsum);
  }

#pragma unroll
  for (int r = 0; r < 4; ++r) {
    float v = lsum[r];
    v += __shfl_xor(v, 1);
    v += __shfl_xor(v, 2);
    v += __shfl_xor(v, 4);
    v += __shfl_xor(v, 8);
    lsum[r] = 1.0f / v;
  }

#pragma unroll
  for (int n = 0; n < 4; ++n)
#pragma unroll
    for (int r = 0; r < 4; ++r) {
      const int qrow = qw + hi * 4 + r;
      const float val = o[n][r] * lsum[r];
      y[(size_t)(b * T_SEQ + qrow) * EMB + h * HD + n * 16 + lo] = f2bf(val);
    }
}

__global__ __launch_bounds__(256, 4) void k_attn(
    const unsigned short* __restrict__ qh,
    const unsigned short* __restrict__ kh,
    const unsigned short* __restrict__ vt,
    unsigned short* __restrict__ y)
{
  __shared__ __align__(16) unsigned short kbuf[2][64 * 64];
  __shared__ __align__(16) unsigned short vbuf[2][64 * 64];
  __shared__ __align__(16) unsigned short pbuf[4 * 16 * 64];

  const int tid = threadIdx.x;
  const int w = tid >> 6, lane = tid & 63;
  const int lo = lane & 15, hi = lane >> 4;
  const int bh = blockIdx.y;
  const int b = bh >> 4, h = bh & 15;

  const unsigned short* Q  = qh + (size_t)bh * T_SEQ * HD;
  const unsigned short* Kp = kh + (size_t)bh * T_SEQ * HD;
  const unsigned short* VT = vt + (size_t)bh * T_SEQ * HD;
  unsigned short* pw = pbuf + w * 1024;

  const int l3 = lane >> 3, l7 = lane & 7;
  const int sw8 = (l7 ^ l3) * 8;
  int koff[2], voff[2];
#pragma unroll
  for (int j = 0; j < 2; ++j) {
    const int row = (2 * w + j) * 8 + l3;
    koff[j] = row * HD + sw8;
    voff[j] = row * T_SEQ + sw8;
  }

  attn_phase(blockIdx.x, w, lo, hi, Q, Kp, VT, koff, voff,
             kbuf[0], kbuf[1], vbuf[0], vbuf[1], pw, y, b, h);
  attn_phase(31 - blockIdx.x, w, lo, hi, Q, Kp, VT, koff, voff,
             kbuf[0], kbuf[1], vbuf[0], vbuf[1], pw, y, b, h);
}

// ---------------- launch ----------------
extern "C" void kernel_launch(void* const* d_in, const int* in_sizes, int n_in,
                              void* d_out, int out_size, void* d_ws, size_t ws_size,
                              hipStream_t stream) {
  const float* x      = (const float*)d_in[0];
  const float* w_qkv  = (const float*)d_in[1];
  const float* b_qkv  = (const float*)d_in[2];
  const float* w_proj = (const float*)d_in[3];
  const float* b_proj = (const float*)d_in[4];
  float* out = (float*)d_out;

  char* ws = (char*)d_ws;
  unsigned short* xb     = (unsigned short*)(ws);                 // 16.78 MB (reused as y)
  unsigned short* wqkvT  = (unsigned short*)(ws + 16777216);      // 6.29 MB
  unsigned short* wprojT = (unsigned short*)(ws + 23068672);      // 2.10 MB
  unsigned short* qhb    = (unsigned short*)(ws + 25165824);      // 16.78 MB
  unsigned short* khb    = (unsigned short*)(ws + 41943040);      // 16.78 MB
  unsigned short* vtb    = (unsigned short*)(ws + 58720256);      // 16.78 MB (V^T)
  unsigned short* yb     = xb;  // x no longer needed after QKV GEMM

  const int lds8 = 2 * SLOT8 * 2;  // 131072 B
  (void)hipFuncSetAttribute(reinterpret_cast<const void*>(k_gemm8p<1>),
                            hipFuncAttributeMaxDynamicSharedMemorySize, lds8);

  k_prep<<<9216, 256, 0, stream>>>(x, xb, w_qkv, wqkvT, w_proj, wprojT);

  k_gemm8p<1><<<dim3(12, 32), 512, lds8, stream>>>(xb, wqkvT, b_qkv, nullptr,
                                                   qhb, khb, vtb, 3 * EMB, EMB);
  k_attn<<<dim3(T_SEQ / 128, NBATCH * NH), 256, 0, stream>>>(qhb, khb, vtb, yb);
  k_gemmq<0><<<dim3(8, 64), 256, 0, stream>>>(yb, wprojT, b_proj, out,
                                              nullptr, nullptr, nullptr, EMB, EMB);
}

// Round 25
// 204.279 us; speedup vs baseline: 1.0329x; 1.0329x over previous
//
#include <hip/hip_runtime.h>
#include <math.h>

#define T_SEQ 2048
#define NH 16
#define HD 64
#define EMB 1024
#define NBATCH 4
#define M_ROWS 8192  // NBATCH*T_SEQ

typedef __attribute__((ext_vector_type(8))) short short8;
typedef __attribute__((ext_vector_type(4))) float f32x4;

__device__ __forceinline__ unsigned short f2bf(float f) {
  unsigned int u = __float_as_uint(f);
  u += 0x7FFF + ((u >> 16) & 1);
  return (unsigned short)(u >> 16);
}

__device__ __forceinline__ float fast_exp2(float x) {
  float r;
  asm("v_exp_f32 %0, %1" : "=v"(r) : "v"(x));
  return r;
}

__device__ __forceinline__ void load_lds16(const void* g, void* l) {
  __builtin_amdgcn_global_load_lds((const __attribute__((address_space(1))) void*)g,
                                   (__attribute__((address_space(3))) void*)l, 16, 0, 0);
}

// ---------------- fused prep: x->bf16 + both weight transposes in ONE dispatch ----------------
__device__ __forceinline__ void cvtT_tile(const float* __restrict__ w,
                                          unsigned short* __restrict__ wt,
                                          int K, int N, int bx, int by,
                                          unsigned short (*tile)[66], int tid) {
  const int k0 = by * 64, n0 = bx * 64;
  const int tc = (tid & 15) * 4;
  const int tr = tid >> 4;
#pragma unroll
  for (int p = 0; p < 4; ++p) {
    const int kr = p * 16 + tr;
    float4 v = *reinterpret_cast<const float4*>(&w[(size_t)(k0 + kr) * N + n0 + tc]);
    tile[kr][tc + 0] = f2bf(v.x); tile[kr][tc + 1] = f2bf(v.y);
    tile[kr][tc + 2] = f2bf(v.z); tile[kr][tc + 3] = f2bf(v.w);
  }
  __syncthreads();
#pragma unroll
  for (int p = 0; p < 4; ++p) {
    const int nr = p * 16 + tr;
    ushort4 o;
    o.x = tile[tc + 0][nr]; o.y = tile[tc + 1][nr];
    o.z = tile[tc + 2][nr]; o.w = tile[tc + 3][nr];
    *reinterpret_cast<ushort4*>(&wt[(size_t)(n0 + nr) * K + k0 + tc]) = o;
  }
}

__global__ __launch_bounds__(256) void k_prep(
    const float* __restrict__ x, unsigned short* __restrict__ xb,
    const float* __restrict__ wqkv, unsigned short* __restrict__ wqkvT,
    const float* __restrict__ wproj, unsigned short* __restrict__ wprojT)
{
  __shared__ unsigned short tile[64][66];
  const int tid = threadIdx.x;
  const int bid = blockIdx.x;

  if (bid < 8192) {
    const int i = bid * 256 + tid;  // n4 = 8192*256 exactly
    float4 v = reinterpret_cast<const float4*>(x)[i];
    ushort4 o;
    o.x = f2bf(v.x); o.y = f2bf(v.y); o.z = f2bf(v.z); o.w = f2bf(v.w);
    reinterpret_cast<ushort4*>(xb)[i] = o;
  } else if (bid < 8960) {
    const int b2 = bid - 8192;  // 768 tiles: 48 x 16
    cvtT_tile(wqkv, wqkvT, EMB, 3 * EMB, b2 % 48, b2 / 48, tile, tid);
  } else {
    const int b2 = bid - 8960;  // 256 tiles: 16 x 16
    cvtT_tile(wproj, wprojT, EMB, EMB, b2 % 16, b2 / 16, tile, tid);
  }
}

// ---------------- GEMM: m97-replica — 128x128 tile, BK=64, 4 waves of 64x64 (best) ----------------
// 256 thr = 2x2 waves, per-wave 64x64 (acc[4][4]), single-buffered 32KB LDS, 2-barrier K-loop.
// XOR swizzle (0 conflicts): source chunk = c ^ (row&7), read chunk = (kk*4+hi) ^ (lo&7).
// Measured plateau of the verified design space at K=1024 (~548 TF); 7 alternative structures
// (pipe-ratio, dbuf/ring/counted-vmcnt, 4-phase, 8-phase, TLP 2-3 blk/CU, B-from-global)
// all landed at or below this.  MODE 0: fp32 out.  MODE 1: scatter q,k -> [B,H,T,64]; v -> V^T.
template <int MODE>
__global__ __launch_bounds__(256, 4) void k_gemmq(
    const unsigned short* __restrict__ A,
    const unsigned short* __restrict__ Bt,
    const float* __restrict__ bias,
    float* __restrict__ Cout,
    unsigned short* __restrict__ qh, unsigned short* __restrict__ kh,
    unsigned short* __restrict__ vh,
    int N, int K)
{
  __shared__ __align__(16) unsigned short sA[128 * 64];  // 16 KB
  __shared__ __align__(16) unsigned short sB[128 * 64];  // 16 KB

  const int tid = threadIdx.x;
  const int w = tid >> 6, lane = tid & 63;
  const int lo = lane & 15, hi = lane >> 4;
  const int wm = w >> 1, wn = w & 1;

  // XCD-aware swizzle (nwg % 8 == 0 for both launches)
  const int nwg = gridDim.x * gridDim.y;
  int flat = blockIdx.y * gridDim.x + blockIdx.x;
  flat = (flat & 7) * (nwg >> 3) + (flat >> 3);
  const int tm = flat / gridDim.x, tn = flat % gridDim.x;

  // staging: thread -> row r0 = tid>>3 (0..31) per 32-row group, chunk = tid&7
  const int r0 = tid >> 3;
  const int scol = ((tid & 7) ^ (r0 & 7)) * 8;   // pre-swizzled source chunk; key (row&7) invariant under +32
  const unsigned short* Ab = A  + (size_t)(tm * 128 + r0) * K + scol;
  const unsigned short* Bb = Bt + (size_t)(tn * 128 + r0) * K + scol;
  const int dsto = tid * 8;                      // linear dest

  const int nkb = K >> 6;  // BK=64
  const int swz = lo & 7;

  f32x4 acc[4][4] = {};

  for (int kb = 0; kb < nkb; ++kb) {
    __syncthreads();  // prior tile's reads retired everywhere
    const int k0 = kb << 6;
#pragma unroll
    for (int i = 0; i < 4; ++i) {   // 4 row-groups of 32; 8 loads/thread total
      load_lds16(Ab + (size_t)(i * 32) * K + k0, sA + i * 2048 + dsto);
      load_lds16(Bb + (size_t)(i * 32) * K + k0, sB + i * 2048 + dsto);
    }
    __syncthreads();  // drains vmcnt -> tile visible

#pragma unroll
    for (int kk = 0; kk < 2; ++kk) {
      short8 a[4], b[4];
#pragma unroll
      for (int m = 0; m < 4; ++m)
        a[m] = *reinterpret_cast<const short8*>(
            &sA[(wm * 64 + m * 16 + lo) * 64 + ((kk * 4 + hi) ^ swz) * 8]);
#pragma unroll
      for (int n = 0; n < 4; ++n)
        b[n] = *reinterpret_cast<const short8*>(
            &sB[(wn * 64 + n * 16 + lo) * 64 + ((kk * 4 + hi) ^ swz) * 8]);
      __builtin_amdgcn_s_setprio(1);
#pragma unroll
      for (int m = 0; m < 4; ++m)
#pragma unroll
        for (int n = 0; n < 4; ++n)
          acc[m][n] = __builtin_amdgcn_mfma_f32_16x16x32_bf16(a[m], b[n], acc[m][n], 0, 0, 0);
      __builtin_amdgcn_s_setprio(0);
    }
  }

#pragma unroll
  for (int m = 0; m < 4; ++m) {
#pragma unroll
    for (int n = 0; n < 4; ++n) {
      const int col = tn * 128 + wn * 64 + n * 16 + lo;
      const float bs = bias[col];
#pragma unroll
      for (int r = 0; r < 4; ++r) {
        const int row = tm * 128 + wm * 64 + m * 16 + hi * 4 + r;
        const float v = acc[m][n][r] + bs;
        if (MODE == 0) {
          Cout[(size_t)row * N + col] = v;
        } else {
          const int sec = col >> 10, jj = col & 1023;
          const int hh = jj >> 6, d = jj & 63;
          const int b2 = row >> 11, tt = row & 2047;
          if (sec == 2) {
            vh[(size_t)((b2 * NH + hh) * HD + d) * T_SEQ + tt] = f2bf(v);  // V^T [B,H,d,T]
          } else {
            unsigned short* dst = sec == 0 ? qh : kh;
            dst[(size_t)((b2 * NH + hh) * T_SEQ + tt) * HD + d] = f2bf(v);
          }
        }
      }
    }
  }
}

// ---------------- flash attention (R16, verified) ----------------
#define C1 0.1803368801111f
#define M2 12.0f

__device__ __forceinline__ void stage2(const unsigned short* src, const int off[2],
                                       unsigned short* dstbase, int w) {
#pragma unroll
  for (int j = 0; j < 2; ++j)
    load_lds16(src + off[j], dstbase + (2 * w + j) * 512);
}

template <bool FIRST, bool LAST>
__device__ __forceinline__ void attn_tile(
    int kvb, int nkvb,  // BOTH in kv-row units
    int qw, int w, int lo, int hi,
    const short8& aq0, const short8& aq1,
    const unsigned short* __restrict__ Kp,
    const unsigned short* __restrict__ VT,
    const int koff[2], const int voff[2],
    unsigned short* kc, unsigned short* kn, unsigned short* vc,
    unsigned short* pw,
    f32x4 o[4], float lsum[4])
{
  {
    const int vb2[2] = {kvb + voff[0], kvb + voff[1]};
    stage2(VT, vb2, vc, w);
  }
  if (!LAST) {
    const int kb2[2] = {nkvb * HD + koff[0], nkvb * HD + koff[1]};
    stage2(Kp, kb2, kn, w);
  }

  if (FIRST)
    asm volatile("s_waitcnt vmcnt(0)\n\ts_barrier" ::: "memory");

  const int swz = lo & 7;
  f32x4 s[4];
#pragma unroll
  for (int n = 0; n < 4; ++n) {
    const int row = (n * 16 + lo) * 64;
    short8 bk0 = *reinterpret_cast<const short8*>(&kc[row + ((hi) ^ swz) * 8]);
    short8 bk1 = *reinterpret_cast<const short8*>(&kc[row + ((4 + hi) ^ swz) * 8]);
    f32x4 z = {};
    z = __builtin_amdgcn_mfma_f32_16x16x32_bf16(aq0, bk0, z, 0, 0, 0);
    s[n] = __builtin_amdgcn_mfma_f32_16x16x32_bf16(aq1, bk1, z, 0, 0, 0);
  }

  const int lb3 = lo >> 3, l7 = lo & 7;
#pragma unroll
  for (int r = 0; r < 4; ++r) {
    const int qrow = qw + hi * 4 + r;
    const int q = hi * 4 + r, qk7 = q & 7;
#pragma unroll
    for (int n = 0; n < 4; ++n) {
      float e = fast_exp2(fmaf(s[n][r], C1, -M2));
      if (LAST) {
        const int kv = kvb + n * 16 + lo;
        if (kv > qrow) e = 0.f;
      }
      lsum[r] += e;
      pw[q * 64 + (((n * 2 + lb3) ^ qk7) * 8) + l7] = f2bf(e);
    }
  }

  asm volatile("s_waitcnt vmcnt(0)\n\ts_barrier" ::: "memory");

#pragma unroll
  for (int kk = 0; kk < 2; ++kk) {
    short8 ap = *reinterpret_cast<const short8*>(&pw[lo * 64 + ((kk * 4 + hi) ^ swz) * 8]);
#pragma unroll
    for (int n = 0; n < 4; ++n) {
      const int row = (n * 16 + lo) * 64;
      short8 bv = *reinterpret_cast<const short8*>(&vc[row + ((kk * 4 + hi) ^ swz) * 8]);
      o[n] = __builtin_amdgcn_mfma_f32_16x16x32_bf16(ap, bv, o[n], 0, 0, 0);
    }
  }
}

__device__ __forceinline__ void attn_phase(
    int qb, int w, int lo, int hi,
    const unsigned short* __restrict__ Q,
    const unsigned short* __restrict__ Kp,
    const unsigned short* __restrict__ VT,
    const int koff[2], const int voff[2],
    unsigned short* kbuf0, unsigned short* kbuf1,
    unsigned short* vbuf0, unsigned short* vbuf1,
    unsigned short* pw,
    unsigned short* __restrict__ y, int b, int h)
{
  __builtin_amdgcn_s_barrier();

  const int qw = qb * 64 + w * 16;

  short8 aq0 = *reinterpret_cast<const short8*>(Q + (size_t)(qw + lo) * HD + hi * 8);
  short8 aq1 = *reinterpret_cast<const short8*>(Q + (size_t)(qw + lo) * HD + 32 + hi * 8);

  f32x4 o[4] = {};
  float lsum[4] = {0.f, 0.f, 0.f, 0.f};

  {
    const int kb2[2] = {koff[0], koff[1]};
    stage2(Kp, kb2, kbuf0, w);
  }

  const int nt = qb + 1;
  if (nt == 1) {
    attn_tile<true, true>(0, 0, qw, w, lo, hi, aq0, aq1, Kp, VT, koff, voff,
                          kbuf0, kbuf1, vbuf0, pw, o, lsum);
  } else {
    attn_tile<true, false>(0, 64, qw, w, lo, hi, aq0, aq1, Kp, VT, koff, voff,
                           kbuf0, kbuf1, vbuf0, pw, o, lsum);
    for (int t = 1; t < nt - 1; ++t) {
      unsigned short* kc = (t & 1) ? kbuf1 : kbuf0;
      unsigned short* kn = (t & 1) ? kbuf0 : kbuf1;
      unsigned short* vc = (t & 1) ? vbuf1 : vbuf0;
      attn_tile<false, false>(t * 64, (t + 1) * 64, qw, w, lo, hi, aq0, aq1, Kp, VT,
                              koff, voff, kc, kn, vc, pw, o, lsum);
    }
    const int t = nt - 1;
    unsigned short* kc = (t & 1) ? kbuf1 : kbuf0;
    unsigned short* kn = (t & 1) ? kbuf0 : kbuf1;
    unsigned short* vc = (t & 1) ? vbuf1 : vbuf0;
    attn_tile<false, true>(t * 64, 0, qw, w, lo, hi, aq0, aq1, Kp, VT, koff, voff,
                           kc, kn, vc, pw, o, lsum);
  }

#pragma unroll
  for (int r = 0; r < 4; ++r) {
    float v = lsum[r];
    v += __shfl_xor(v, 1);
    v += __shfl_xor(v, 2);
    v += __shfl_xor(v, 4);
    v += __shfl_xor(v, 8);
    lsum[r] = 1.0f / v;
  }

#pragma unroll
  for (int n = 0; n < 4; ++n)
#pragma unroll
    for (int r = 0; r < 4; ++r) {
      const int qrow = qw + hi * 4 + r;
      const float val = o[n][r] * lsum[r];
      y[(size_t)(b * T_SEQ + qrow) * EMB + h * HD + n * 16 + lo] = f2bf(val);
    }
}

__global__ __launch_bounds__(256, 4) void k_attn(
    const unsigned short* __restrict__ qh,
    const unsigned short* __restrict__ kh,
    const unsigned short* __restrict__ vt,
    unsigned short* __restrict__ y)
{
  __shared__ __align__(16) unsigned short kbuf[2][64 * 64];
  __shared__ __align__(16) unsigned short vbuf[2][64 * 64];
  __shared__ __align__(16) unsigned short pbuf[4 * 16 * 64];

  const int tid = threadIdx.x;
  const int w = tid >> 6, lane = tid & 63;
  const int lo = lane & 15, hi = lane >> 4;
  const int bh = blockIdx.y;
  const int b = bh >> 4, h = bh & 15;

  const unsigned short* Q  = qh + (size_t)bh * T_SEQ * HD;
  const unsigned short* Kp = kh + (size_t)bh * T_SEQ * HD;
  const unsigned short* VT = vt + (size_t)bh * T_SEQ * HD;
  unsigned short* pw = pbuf + w * 1024;

  const int l3 = lane >> 3, l7 = lane & 7;
  const int sw8 = (l7 ^ l3) * 8;
  int koff[2], voff[2];
#pragma unroll
  for (int j = 0; j < 2; ++j) {
    const int row = (2 * w + j) * 8 + l3;
    koff[j] = row * HD + sw8;
    voff[j] = row * T_SEQ + sw8;
  }

  attn_phase(blockIdx.x, w, lo, hi, Q, Kp, VT, koff, voff,
             kbuf[0], kbuf[1], vbuf[0], vbuf[1], pw, y, b, h);
  attn_phase(31 - blockIdx.x, w, lo, hi, Q, Kp, VT, koff, voff,
             kbuf[0], kbuf[1], vbuf[0], vbuf[1], pw, y, b, h);
}

// ---------------- launch ----------------
extern "C" void kernel_launch(void* const* d_in, const int* in_sizes, int n_in,
                              void* d_out, int out_size, void* d_ws, size_t ws_size,
                              hipStream_t stream) {
  const float* x      = (const float*)d_in[0];
  const float* w_qkv  = (const float*)d_in[1];
  const float* b_qkv  = (const float*)d_in[2];
  const float* w_proj = (const float*)d_in[3];
  const float* b_proj = (const float*)d_in[4];
  float* out = (float*)d_out;

  char* ws = (char*)d_ws;
  unsigned short* xb     = (unsigned short*)(ws);                 // 16.78 MB (reused as y)
  unsigned short* wqkvT  = (unsigned short*)(ws + 16777216);      // 6.29 MB
  unsigned short* wprojT = (unsigned short*)(ws + 23068672);      // 2.10 MB
  unsigned short* qhb    = (unsigned short*)(ws + 25165824);      // 16.78 MB
  unsigned short* khb    = (unsigned short*)(ws + 41943040);      // 16.78 MB
  unsigned short* vtb    = (unsigned short*)(ws + 58720256);      // 16.78 MB (V^T)
  unsigned short* yb     = xb;  // x no longer needed after QKV GEMM

  // one fused prep dispatch: x->bf16 (8192 blocks) + w_qkv^T (768) + w_proj^T (256)
  k_prep<<<9216, 256, 0, stream>>>(x, xb, w_qkv, wqkvT, w_proj, wprojT);

  k_gemmq<1><<<dim3(24, 64), 256, 0, stream>>>(xb, wqkvT, b_qkv, nullptr,
                                               qhb, khb, vtb, 3 * EMB, EMB);
  k_attn<<<dim3(T_SEQ / 128, NBATCH * NH), 256, 0, stream>>>(qhb, khb, vtb, yb);
  k_gemmq<0><<<dim3(8, 64), 256, 0, stream>>>(yb, wprojT, b_proj, out,
                                              nullptr, nullptr, nullptr, EMB, EMB);
}